// Round 1
// 270.734 us; speedup vs baseline: 1.0161x; 1.0161x over previous
//
#include <hip/hip_runtime.h>

#define NPTS 65536
#define KC   1024
#define DD   512

using bf16x8 = __attribute__((ext_vector_type(8))) __bf16;
using f32x4  = __attribute__((ext_vector_type(4))) float;

// ---- async global->LDS, 16B per lane. LDS dest = wave-uniform base + lane*16.
__device__ __forceinline__ void gld_lds16(const void* g, void* lds_base) {
  __builtin_amdgcn_global_load_lds(
      (const __attribute__((address_space(1))) unsigned int*)(uintptr_t)g,
      (__attribute__((address_space(3))) unsigned int*)(unsigned int)(uintptr_t)lds_base,
      16, 0, 0);
}

// pack float4 -> 4 bf16 (truncation)
__device__ __forceinline__ uint2 pack4(const float4& v) {
  uint2 r;
  r.x = (__float_as_uint(v.x) >> 16) | (__float_as_uint(v.y) & 0xffff0000u);
  r.y = (__float_as_uint(v.z) >> 16) | (__float_as_uint(v.w) & 0xffff0000u);
  return r;
}

// ================= FAST PATH =================

// merged prep: blocks [0,16384) = one wave per x row: convert x->bf16 and
// accumulate the exact-fp32 loss term ||x_i - c_{y[i]}||^2.
// blocks [16384,16640) = centers->cb + c2.   (unchanged — not the bottleneck)
__global__ __launch_bounds__(256) void prep_kernel(
    const float* __restrict__ x, const int* __restrict__ y,
    const float* __restrict__ centers, uint4* __restrict__ xb,
    uint4* __restrict__ cb, float* __restrict__ c2,
    float* __restrict__ partial) {
  const int w = threadIdx.x >> 6, l = threadIdx.x & 63;
  if (blockIdx.x >= 16384) {   // centers section
    const int row = (blockIdx.x - 16384) * 4 + w;
    const float4* cf4 = (const float4*)centers;
    float4 a = cf4[row * 128 + 2 * l];
    float4 b = cf4[row * 128 + 2 * l + 1];
    uint2 pa = pack4(a), pb = pack4(b);
    cb[row * 64 + l] = make_uint4(pa.x, pa.y, pb.x, pb.y);
    float s = a.x * a.x + a.y * a.y + a.z * a.z + a.w * a.w +
              b.x * b.x + b.y * b.y + b.z * b.z + b.w * b.w;
#pragma unroll
    for (int off = 32; off; off >>= 1) s += __shfl_down(s, off, 64);
    if (l == 0) c2[row] = s;
    return;
  }
  const int row = blockIdx.x * 4 + w;
  const float4* xr = (const float4*)(x + (size_t)row * DD);
  float4 a = xr[2 * l];
  float4 b = xr[2 * l + 1];
  uint2 pa = pack4(a), pb = pack4(b);
  xb[row * 64 + l] = make_uint4(pa.x, pa.y, pb.x, pb.y);
  const int yr = y[row];
  const float4* cr = (const float4*)(centers + (size_t)yr * DD);
  float4 ca = cr[2 * l];
  float4 cb2 = cr[2 * l + 1];
  float d0 = a.x - ca.x, d1 = a.y - ca.y, d2 = a.z - ca.z, d3 = a.w - ca.w;
  float d4 = b.x - cb2.x, d5 = b.y - cb2.y, d6 = b.z - cb2.z, d7 = b.w - cb2.w;
  float s = d0 * d0 + d1 * d1 + d2 * d2 + d3 * d3 +
            d4 * d4 + d5 * d5 + d6 * d6 + d7 * d7;
#pragma unroll
  for (int off = 32; off; off >>= 1) s += __shfl_down(s, off, 64);
  __shared__ float ps[4];
  if (l == 0) ps[w] = s;
  __syncthreads();
  if (threadIdx.x == 0) partial[blockIdx.x] = ps[0] + ps[1] + ps[2] + ps[3];
}

// bf16 MFMA argmin — counted-vmcnt ring pipeline (T3+T4+T5).
//
// Geometry: BM=256 rows/block, 512 threads = 8 waves (wm=w>>1 in 0..3 row
// quarter, wn=w&1 col half), BN=256 per n0 pass (4 passes), BK=32.
// Per tile t (t=0..63: n0i=t>>4, ks=t&15): A,B tiles are 256x32 bf16 =16KB
// each, staged into a 4-slot LDS ring (slot t&3).  Per-thread 4 gld_lds/tile.
//
// Staging window = 16 rows x 4 uint4 = 1024B = one gld_lds per wave; with
// BK=32 the window exactly matches the 16-row MFMA fragment span, so a plain
// LINEAR layout (pos = row*4 + kchunk) is a per-window bijection for the
// fragment read (lane(m16,q4) -> chunk m16*4+q4) -> uniform 8/bank, no
// swizzle needed, 0 conflicts.
//
// Pipeline invariants (race-free by construction):
//  - stage of tile t+2 (issued inside group t, after the entry barrier)
//    overwrites slot of tile t-2, whose reads finished 2 barrier-groups ago.
//  - boundary = s_waitcnt vmcnt(4); s_barrier: the 4 in-flight loads are
//    tile t+2's; everything older (tile t+1) is forced complete.  vmcnt
//    NEVER drains to 0 in steady state (tail: vmcnt(0) only at t>=62).
//  - NO __syncthreads in the main loop (it would emit vmcnt(0)).
// Registers: acc 128 + best/bi 32 + frags 48 + addr ~20 ~= 225 < 256 cap
// at __launch_bounds__(512,2).  LDS: 64KB A ring + 64KB B ring + 4KB c2s.
__global__ __launch_bounds__(512, 2) void gemm_argmin(
    const uint4* __restrict__ xb, const uint4* __restrict__ cb,
    const float* __restrict__ c2, float* __restrict__ ynew_out) {
  __shared__ uint4 As[4096];   // 4 ring slots x (256 rows x 4 k-chunks)
  __shared__ uint4 Bs[4096];
  __shared__ float c2s[KC];

  const int t = threadIdx.x;
  const int w = t >> 6, l = t & 63;
  const int wm = w >> 1, wn = w & 1;     // wave tile: 64 rows x 128 cols
  const int q4 = l >> 4, m16 = l & 15;
  const int row0 = blockIdx.x * 256;

  c2s[t] = c2[t];
  c2s[t + 512] = c2[t + 512];

  // per-thread staging source bases (uint4 units): lane l covers row l>>2 of
  // its wave's 16-row window, k-chunk l&3.  Window w+8 = +128 rows = +8192.
  const uint4* aB = xb + ((size_t)(row0 + w * 16 + (l >> 2)) * 64 + (l & 3));
  const uint4* bB = cb + ((size_t)(w * 16 + (l >> 2)) * 64 + (l & 3));

  // prologue: stage tiles 0 (slot 0) and 1 (slot 1)
  gld_lds16(aB, &As[w * 64]);
  gld_lds16(aB + 8192, &As[w * 64 + 512]);
  gld_lds16(bB, &Bs[w * 64]);
  gld_lds16(bB + 8192, &Bs[w * 64 + 512]);
  gld_lds16(aB + 4, &As[1024 + w * 64]);
  gld_lds16(aB + 8196, &As[1024 + w * 64 + 512]);
  gld_lds16(bB + 4, &Bs[1024 + w * 64]);
  gld_lds16(bB + 8196, &Bs[1024 + w * 64 + 512]);

  f32x4 acc[4][8];
#pragma unroll
  for (int i = 0; i < 4; i++)
#pragma unroll
    for (int j = 0; j < 8; j++) acc[i][j] = (f32x4){0.f, 0.f, 0.f, 0.f};

  float best[16];
  int bi_[16];
#pragma unroll
  for (int i = 0; i < 16; i++) { best[i] = 3.4e38f; bi_[i] = 0; }

  asm volatile("s_waitcnt vmcnt(4)" ::: "memory");  // tile 0 landed; tile 1 in flight
  __builtin_amdgcn_s_barrier();

#pragma unroll 4
  for (int tt = 0; tt < 64; ++tt) {
    const int bse = (tt & 3) * 1024;
    bf16x8 af[4], bf0[4], bf1[4];
    // phase 0: fragments for C-half j=0..3, prefetch A of tile tt+2
#pragma unroll
    for (int i = 0; i < 4; i++)
      af[i] = *(const bf16x8*)&As[bse + (wm * 64 + i * 16 + m16) * 4 + q4];
#pragma unroll
    for (int j = 0; j < 4; j++)
      bf0[j] = *(const bf16x8*)&Bs[bse + (wn * 128 + j * 16 + m16) * 4 + q4];
    if (tt < 62) {
      const int s2 = ((tt + 2) & 3) * 1024;
      const int oa = ((tt + 2) & 15) * 4;
      gld_lds16(aB + oa, &As[s2 + w * 64]);
      gld_lds16(aB + 8192 + oa, &As[s2 + w * 64 + 512]);
    }
    __builtin_amdgcn_s_setprio(1);
#pragma unroll
    for (int j = 0; j < 4; j++)
#pragma unroll
      for (int i = 0; i < 4; i++)
        acc[i][j] = __builtin_amdgcn_mfma_f32_16x16x32_bf16(af[i], bf0[j], acc[i][j], 0, 0, 0);
    __builtin_amdgcn_s_setprio(0);
    // phase 1: C-half j=4..7, prefetch B of tile tt+2
#pragma unroll
    for (int j = 0; j < 4; j++)
      bf1[j] = *(const bf16x8*)&Bs[bse + (wn * 128 + (j + 4) * 16 + m16) * 4 + q4];
    if (tt < 62) {
      const int s2 = ((tt + 2) & 3) * 1024;
      const int ob = ((tt + 2) >> 4) * 16384 + ((tt + 2) & 15) * 4;
      gld_lds16(bB + ob, &Bs[s2 + w * 64]);
      gld_lds16(bB + ob + 8192, &Bs[s2 + w * 64 + 512]);
    }
    __builtin_amdgcn_s_setprio(1);
#pragma unroll
    for (int j = 0; j < 4; j++)
#pragma unroll
      for (int i = 0; i < 4; i++)
        acc[i][j + 4] = __builtin_amdgcn_mfma_f32_16x16x32_bf16(af[i], bf1[j], acc[i][j + 4], 0, 0, 0);
    __builtin_amdgcn_s_setprio(0);

    // fold tile into running argmin at each n0 boundary (register-only).
    // C/D: col=lane&15, row=(lane>>4)*4+reg
    if ((tt & 15) == 15) {
      const int n0 = (tt >> 4) * 256;
#pragma unroll
      for (int j = 0; j < 8; j++) {
        const int n = n0 + wn * 128 + j * 16 + m16;
        const float cc = c2s[n];
#pragma unroll
        for (int i = 0; i < 4; i++)
#pragma unroll
          for (int r = 0; r < 4; r++) {
            float v = fmaf(-2.f, acc[i][j][r], cc);
            const int bi = i * 4 + r;
            if (v < best[bi]) { best[bi] = v; bi_[bi] = n; }
            acc[i][j][r] = 0.f;
          }
      }
    }

    // boundary: force tile tt+1 resident; keep tile tt+2's 4 loads in flight
    if (tt < 62) asm volatile("s_waitcnt vmcnt(4)" ::: "memory");
    else         asm volatile("s_waitcnt vmcnt(0)" ::: "memory");
    __builtin_amdgcn_s_barrier();
  }

  // per-wave merge across the 16 columns held by the m16 lanes
  float* mv = (float*)As;                 // [2][256] values   (As is free now)
  int*   mi = (int*)((char*)As + 2048);   // [2][256] indices
#pragma unroll
  for (int bi = 0; bi < 16; bi++) {
    float v = best[bi];
    int idx = bi_[bi];
#pragma unroll
    for (int off = 8; off; off >>= 1) {
      float ov = __shfl_xor(v, off, 64);
      int oi = __shfl_xor(idx, off, 64);
      if (ov < v || (ov == v && oi < idx)) { v = ov; idx = oi; }
    }
    if (m16 == 0) {
      const int m = wm * 64 + (bi >> 2) * 16 + q4 * 4 + (bi & 3);
      mv[wn * 256 + m] = v;
      mi[wn * 256 + m] = idx;
    }
  }
  __syncthreads();
  // cross-wn merge (fixes the two-col-half write race of the old epilogue)
  if (t < 256) {
    float v0 = mv[t], v1 = mv[256 + t];
    int i0 = mi[t], i1 = mi[256 + t];
    const int idx = (v1 < v0 || (v1 == v0 && i1 < i0)) ? i1 : i0;
    ynew_out[row0 + t] = (float)idx;
  }
}

__global__ __launch_bounds__(256) void loss_final(const float* __restrict__ partial,
                                                  float* __restrict__ out) {
  float s = 0.f;
#pragma unroll
  for (int j = 0; j < 64; j++) s += partial[threadIdx.x + 256 * j];
#pragma unroll
  for (int off = 32; off; off >>= 1) s += __shfl_down(s, off, 64);
  __shared__ float ps[4];
  if ((threadIdx.x & 63) == 0) ps[threadIdx.x >> 6] = s;
  __syncthreads();
  if (threadIdx.x == 0) out[0] = ps[0] + ps[1] + ps[2] + ps[3];
}

// ================= FALLBACK PATH (unchanged, used only if ws too small) =================

#define SLOT(row, oct) (16 * (oct) + (((row) & 15) ^ (((oct) & 2) << 1)))

__device__ __forceinline__ void split_pack(const float4& a, const float4& b,
                                           uint4& hi, uint4& lo) {
  float f[8] = {a.x, a.y, a.z, a.w, b.x, b.y, b.z, b.w};
  uint hw[4], lw[4];
#pragma unroll
  for (int i = 0; i < 4; i++) {
    uint e0 = __float_as_uint(f[2 * i]), e1 = __float_as_uint(f[2 * i + 1]);
    hw[i] = (e0 >> 16) | (e1 & 0xffff0000u);
    float l0 = f[2 * i]     - __uint_as_float(e0 & 0xffff0000u);
    float l1 = f[2 * i + 1] - __uint_as_float(e1 & 0xffff0000u);
    lw[i] = (__float_as_uint(l0) >> 16) | (__float_as_uint(l1) & 0xffff0000u);
  }
  hi = make_uint4(hw[0], hw[1], hw[2], hw[3]);
  lo = make_uint4(lw[0], lw[1], lw[2], lw[3]);
}

__global__ __launch_bounds__(256) void c2_kernel(const float* __restrict__ centers,
                                                 float* __restrict__ c2) {
  int wave = (blockIdx.x * 256 + threadIdx.x) >> 6;
  int lane = threadIdx.x & 63;
  const float4* c4 = (const float4*)(centers + (size_t)wave * DD);
  float s = 0.f;
#pragma unroll
  for (int j = 0; j < 2; j++) {
    float4 v = c4[lane + 64 * j];
    s += v.x * v.x + v.y * v.y + v.z * v.z + v.w * v.w;
  }
#pragma unroll
  for (int off = 32; off; off >>= 1) s += __shfl_down(s, off, 64);
  if (lane == 0) c2[wave] = s;
}

__global__ __launch_bounds__(256, 2) void argmin_fb(
    const float* __restrict__ x, const float* __restrict__ centers,
    const float* __restrict__ c2, float* __restrict__ ynew_out) {
  __shared__ uint4 Ah[512], Al[512], Bh[512], Bl[512];
  const int t = threadIdx.x;
  const int w = t >> 6, l = t & 63;
  const int wm = w >> 1, wn = w & 1;
  const size_t row0 = (size_t)blockIdx.x * 128;
  const int srow = t >> 1, h = t & 1;
  const int mt = srow >> 4;
  const int so0 = mt * 64 + SLOT(srow, 2 * h);
  const int so1 = mt * 64 + SLOT(srow, 2 * h + 1);
  const int rs = SLOT(l & 15, l >> 4);
  const float* xp = x + (row0 + srow) * DD + h * 16;
  float best[16];
  int bidx[16];
#pragma unroll
  for (int i = 0; i < 16; i++) { best[i] = 3.4e38f; bidx[i] = 0; }
  for (int n0 = 0; n0 < KC; n0 += 128) {
    const float* bp = centers + (size_t)(n0 + srow) * DD + h * 16;
    f32x4 acc[4][4];
#pragma unroll
    for (int i = 0; i < 4; i++)
#pragma unroll
      for (int j = 0; j < 4; j++) acc[i][j] = (f32x4){0.f, 0.f, 0.f, 0.f};
    float4 ra[4], rb[4];
#pragma unroll
    for (int q = 0; q < 4; q++) {
      ra[q] = *(const float4*)(xp + q * 4);
      rb[q] = *(const float4*)(bp + q * 4);
    }
    for (int ks = 0; ks < 16; ks++) {
      uint4 ah0, al0, ah1, al1, bh0, bl0, bh1, bl1;
      split_pack(ra[0], ra[1], ah0, al0);
      split_pack(ra[2], ra[3], ah1, al1);
      split_pack(rb[0], rb[1], bh0, bl0);
      split_pack(rb[2], rb[3], bh1, bl1);
      __syncthreads();
      Ah[so0] = ah0; Al[so0] = al0;
      Ah[so1] = ah1; Al[so1] = al1;
      Bh[so0] = bh0; Bl[so0] = bl0;
      Bh[so1] = bh1; Bl[so1] = bl1;
      __syncthreads();
      if (ks < 15) {
#pragma unroll
        for (int q = 0; q < 4; q++) {
          ra[q] = *(const float4*)(xp + (ks + 1) * 32 + q * 4);
          rb[q] = *(const float4*)(bp + (ks + 1) * 32 + q * 4);
        }
      }
      bf16x8 afh[4], afl[4], bfh[4], bfl[4];
#pragma unroll
      for (int i = 0; i < 4; i++) {
        afh[i] = *(const bf16x8*)&Ah[(wm * 4 + i) * 64 + rs];
        afl[i] = *(const bf16x8*)&Al[(wm * 4 + i) * 64 + rs];
        bfh[i] = *(const bf16x8*)&Bh[(wn * 4 + i) * 64 + rs];
        bfl[i] = *(const bf16x8*)&Bl[(wn * 4 + i) * 64 + rs];
      }
#pragma unroll
      for (int i = 0; i < 4; i++)
#pragma unroll
        for (int j = 0; j < 4; j++) {
          acc[i][j] = __builtin_amdgcn_mfma_f32_16x16x32_bf16(afh[i], bfh[j], acc[i][j], 0, 0, 0);
          acc[i][j] = __builtin_amdgcn_mfma_f32_16x16x32_bf16(afl[i], bfh[j], acc[i][j], 0, 0, 0);
          acc[i][j] = __builtin_amdgcn_mfma_f32_16x16x32_bf16(afh[i], bfl[j], acc[i][j], 0, 0, 0);
        }
    }
#pragma unroll
    for (int j = 0; j < 4; j++) {
      int n = n0 + wn * 64 + j * 16 + (l & 15);
      float cc = c2[n];
#pragma unroll
      for (int i = 0; i < 4; i++)
#pragma unroll
        for (int r = 0; r < 4; r++) {
          float v = fmaf(-2.f, acc[i][j][r], cc);
          int bi = i * 4 + r;
          if (v < best[bi]) { best[bi] = v; bidx[bi] = n; }
        }
    }
  }
#pragma unroll
  for (int bi = 0; bi < 16; bi++) {
    float v = best[bi];
    int idx = bidx[bi];
#pragma unroll
    for (int off = 8; off; off >>= 1) {
      float ov = __shfl_xor(v, off, 64);
      int oi = __shfl_xor(idx, off, 64);
      if (ov < v || (ov == v && oi < idx)) { v = ov; idx = oi; }
    }
    if ((l & 15) == 0) {
      int m = wm * 64 + (bi >> 2) * 16 + (l >> 4) * 4 + (bi & 3);
      ynew_out[row0 + m] = (float)idx;
    }
  }
}

__global__ __launch_bounds__(256) void loss_partial_fb(
    const float* __restrict__ x, const int* __restrict__ y,
    const float* __restrict__ centers, float* __restrict__ partial) {
  const int w = threadIdx.x >> 6, l = threadIdx.x & 63;
  const int row = blockIdx.x * 4 + w;
  const float4* x4 = (const float4*)(x + (size_t)row * DD);
  const float4* c4 = (const float4*)(centers + (size_t)y[row] * DD);
  float s = 0.f;
#pragma unroll
  for (int j = 0; j < 2; j++) {
    float4 xv = x4[2 * l + j], cv = c4[2 * l + j];
    float dx = xv.x - cv.x, dy = xv.y - cv.y, dz = xv.z - cv.z, dw = xv.w - cv.w;
    s += dx * dx + dy * dy + dz * dz + dw * dw;
  }
#pragma unroll
  for (int off = 32; off; off >>= 1) s += __shfl_down(s, off, 64);
  __shared__ float ps[4];
  if (l == 0) ps[w] = s;
  __syncthreads();
  if (threadIdx.x == 0) partial[blockIdx.x] = ps[0] + ps[1] + ps[2] + ps[3];
}

// ================= launcher =================

extern "C" void kernel_launch(void* const* d_in, const int* in_sizes, int n_in,
                              void* d_out, int out_size, void* d_ws, size_t ws_size,
                              hipStream_t stream) {
  const float* x       = (const float*)d_in[0];
  const int*   y       = (const int*)d_in[1];
  const float* centers = (const float*)d_in[2];
  float* out = (float*)d_out;  // out[0] = loss, out[1..] = ynew as float

  const size_t xb_bytes = (size_t)NPTS * DD * 2;  // 64 MB
  const size_t cb_bytes = (size_t)KC * DD * 2;    // 1 MB
  const size_t need = xb_bytes + cb_bytes + (KC + NPTS / 4) * sizeof(float);

  if (ws_size >= need) {
    uint4* xb      = (uint4*)d_ws;
    uint4* cbp     = (uint4*)((char*)d_ws + xb_bytes);
    float* c2      = (float*)((char*)d_ws + xb_bytes + cb_bytes);
    float* partial = c2 + KC;        // 16384 floats
    prep_kernel<<<16384 + 256, 256, 0, stream>>>(x, y, centers, xb, cbp, c2, partial);
    gemm_argmin<<<NPTS / 256, 512, 0, stream>>>(xb, cbp, c2, out + 1);
    loss_final<<<1, 256, 0, stream>>>(partial, out);
  } else {
    float* c2      = (float*)d_ws;
    float* partial = c2 + KC;
    c2_kernel<<<KC / 4, 256, 0, stream>>>(centers, c2);
    argmin_fb<<<NPTS / 128, 256, 0, stream>>>(x, centers, c2, out + 1);
    loss_partial_fb<<<NPTS / 4, 256, 0, stream>>>(x, y, centers, partial);
    loss_final<<<1, 256, 0, stream>>>(partial, out);
  }
}